// Round 6
// baseline (982.025 us; speedup 1.0000x reference)
//
#include <hip/hip_runtime.h>
#include <hip/hip_bf16.h>
#include <math.h>

#define VOCAB 50257
#define NCLS 20
#define EDIM 64
#define HDIM 64
#define BATCH 128
#define TLEN 2048

typedef float v2f __attribute__((ext_vector_type(2)));

// Static device scratch: no dependence on ws_size, graph-capture safe.
__device__ float g_P[(size_t)2 * VOCAB * 192];   // 77.2 MB, input-projected vocab table (bias folded)
__device__ float g_feats[BATCH * 256];           // pooled features

__device__ __forceinline__ float fast_rcp(float x) { return __builtin_amdgcn_rcpf(x); }

__device__ __forceinline__ float fsigmoid(float x) {
    // 1/(1+exp(-x)); saturates correctly at +-inf
    return fast_rcp(1.f + __expf(-x));
}
__device__ __forceinline__ float ftanh(float x) {
    // 1 - 2/(exp(2x)+1); saturates correctly at +-inf
    float e = __expf(2.f * x);
    return 1.f - 2.f * fast_rcp(e + 1.f);
}

// ---------------- Kernel A: P[dir][v][g] = dot(emb[v], wih[dir][g]) + bih[dir][g] ----------------
// Weights kept in 16 NAMED float4 registers (an array would be memory-backed by the compiler:
// rounds 0-5 showed per-thread arrays land in scratch, not VGPRs -- the dominant hidden cost).
__global__ __launch_bounds__(384) void precompute_P(
    const float* __restrict__ emb,
    const float* __restrict__ wih_f, const float* __restrict__ bih_f,
    const float* __restrict__ wih_b, const float* __restrict__ bih_b)
{
    const int t = threadIdx.x;          // 0..383 ; waves are uniform in (dir), contiguous in g
    const int dir = t / 192;
    const int g = t % 192;
    const float* wih = dir ? wih_b : wih_f;
    const float* bih = dir ? bih_b : bih_f;

    float4 wq0, wq1, wq2, wq3, wq4, wq5, wq6, wq7;
    float4 wq8, wq9, wq10, wq11, wq12, wq13, wq14, wq15;
#define LDWQ(K) wq##K = *(const float4*)(wih + (size_t)g * 64 + 4 * K)
    LDWQ(0); LDWQ(1); LDWQ(2); LDWQ(3); LDWQ(4); LDWQ(5); LDWQ(6); LDWQ(7);
    LDWQ(8); LDWQ(9); LDWQ(10); LDWQ(11); LDWQ(12); LDWQ(13); LDWQ(14); LDWQ(15);
#undef LDWQ
    const float bias = bih[g];
    float* Pd = g_P + (size_t)dir * VOCAB * 192;

    for (int v = blockIdx.x * 2; v < VOCAB; v += gridDim.x * 2) {
        const int v1ok = (v + 1 < VOCAB);
        const float4* e0 = (const float4*)(emb + (size_t)v * 64);            // wave-uniform -> scalar loads
        const float4* e1 = (const float4*)(emb + (size_t)(v1ok ? v + 1 : v) * 64);
        float a0 = bias, a1 = bias;
#define PFMA(K) do {                                   \
            float4 x = e0[K];                          \
            float4 y = e1[K];                          \
            a0 = fmaf(x.x, wq##K.x, a0);               \
            a1 = fmaf(y.x, wq##K.x, a1);               \
            a0 = fmaf(x.y, wq##K.y, a0);               \
            a1 = fmaf(y.y, wq##K.y, a1);               \
            a0 = fmaf(x.z, wq##K.z, a0);               \
            a1 = fmaf(y.z, wq##K.z, a1);               \
            a0 = fmaf(x.w, wq##K.w, a0);               \
            a1 = fmaf(y.w, wq##K.w, a1);               \
        } while (0)
        PFMA(0); PFMA(1); PFMA(2); PFMA(3); PFMA(4); PFMA(5); PFMA(6); PFMA(7);
        PFMA(8); PFMA(9); PFMA(10); PFMA(11); PFMA(12); PFMA(13); PFMA(14); PFMA(15);
#undef PFMA
        Pd[(size_t)v * 192 + g] = a0;
        if (v1ok) Pd[(size_t)(v + 1) * 192 + g] = a1;
    }
}

// ---------------- Kernel B: 3 waves per (dir,batch) sequence — wave = gate ----------------
// wave g (0=r,1=z,2=n), lane u owns whh row g*64+u: 64 weight floats/lane held in 32 NAMED
// v2f registers. KEY CHANGE vs round 5: round 5 used `v2f w[32]` and reported VGPR_Count=52
// -- too few to hold 64 floats, i.e. the array was an alloca in SCRATCH, reloaded (16 float4
// tracked vmem loads + compiler vmcnt waits) EVERY step. That scratch reload chain, present
// in every prior round's weight arrays, is the ~1000 cyc/step invariant. Named scalars are
// guaranteed regalloc candidates (~100 VGPR demand < 128 budget => zero scratch).
//
// Everything else identical to round 5 (verified, absmax 0.0): depth-4 asm ring with
// s_waitcnt vmcnt(3) tied to the slot register; raw s_barrier + asm lgkmcnt(0) (never
// __syncthreads -- its vmcnt(0) drain would kill the ring); wave2 combines and pools.
__global__ __launch_bounds__(192, 1) void gru_seq(
    const int* __restrict__ tokens,
    const float* __restrict__ whh_f, const float* __restrict__ bhh_f,
    const float* __restrict__ whh_b, const float* __restrict__ bhh_b)
{
    const int tid = threadIdx.x;
    const int wid = tid >> 6;            // 0=r, 1=z, 2=n/combiner (wave-uniform)
    const int lane = tid & 63;           // hidden unit index
    const int blk = blockIdx.x;          // 0..255
    const int b = blk >> 1;
    const int dir = blk & 1;
    const float* whh = dir ? whh_b : whh_f;
    const float* bhh = dir ? bhh_b : bhh_f;
    // per-thread gather base: this gate's element for unit `lane`
    const float* Pd = g_P + (size_t)dir * VOCAB * 192 + wid * 64 + lane;

    __shared__ __align__(16) float h_lds[64];
    __shared__ float r_lds[64];
    __shared__ float z_lds[64];
    __shared__ __align__(16) int tok_lds[TLEN];

    // stage token row (8 KB) once, vectorized across 192 threads
    {
        const int4* src = (const int4*)(tokens + (size_t)b * TLEN);
        int4* dst = (int4*)tok_lds;
        for (int t = tid; t < TLEN / 4; t += 192) dst[t] = src[t];
    }

    // per-lane whh row for this wave's gate -> 32 NAMED v2f regs (64 VGPRs, register-resident)
    v2f wa0, wa1, wa2, wa3, wa4, wa5, wa6, wa7, wa8, wa9, wa10, wa11, wa12, wa13, wa14, wa15;
    v2f wb0, wb1, wb2, wb3, wb4, wb5, wb6, wb7, wb8, wb9, wb10, wb11, wb12, wb13, wb14, wb15;
    {
        const float* p = whh + (size_t)(wid * 64 + lane) * 64;
#define LDW(K) do { float4 a_ = *(const float4*)(p + 4 * K);                  \
        wa##K = (v2f){a_.x, a_.y}; wb##K = (v2f){a_.z, a_.w}; } while (0)
        LDW(0); LDW(1); LDW(2); LDW(3); LDW(4); LDW(5); LDW(6); LDW(7);
        LDW(8); LDW(9); LDW(10); LDW(11); LDW(12); LDW(13); LDW(14); LDW(15);
#undef LDW
    }
    const float bias = bhh[wid * 64 + lane];

    if (wid == 2) h_lds[lane] = 0.f;
    float h = 0.f, sum = 0.f, mx = -INFINITY;   // h/sum/mx live in wave2 only
    __syncthreads();    // prologue-only: tok_lds + h_lds visible (vmcnt drain harmless here)

    // time mapping: step s -> tt = dir ? T-1-s : s
    auto tok_at = [&](int s) -> int {
        int ss = s < TLEN ? s : TLEN - 1;        // clamp for tail prefetches (values unused)
        return tok_lds[dir ? (TLEN - 1 - ss) : ss];
    };

    // depth-4 ring: 4 named regs per wave, defined ONLY by asm loads (1 load/step/wave)
    float x0, x1, x2, x3;
#define GRU_PRE(SL, D) \
    asm volatile("global_load_dword %0, %1, off" : "=v"(x##SL) : "v"(Pd + (size_t)tok_at(D) * 192))
    GRU_PRE(0, 0); GRU_PRE(1, 1); GRU_PRE(2, 2); GRU_PRE(3, 3);

    // one FMA pair of the h-dot; identical accumulation order to rounds 0-5 (absmax 0.0)
#define DOT(K, A0, A1) do {                                                        \
        float4 h4_ = *(const float4*)(h_lds + 4 * K);                              \
        A0 = __builtin_elementwise_fma((v2f){h4_.x, h4_.y}, wa##K, A0);            \
        A1 = __builtin_elementwise_fma((v2f){h4_.z, h4_.w}, wb##K, A1);            \
    } while (0)

#define GRU_STEP(SL, SB) do {                                                      \
        const int tN_ = tok_at((SB) + 4);   /* broadcast LDS read, off critical path */ \
        v2f a0 = {0.f, 0.f}, a1 = {0.f, 0.f};                                      \
        DOT(0, a0, a1);  DOT(1, a0, a1);  DOT(2, a0, a1);  DOT(3, a0, a1);         \
        DOT(4, a0, a1);  DOT(5, a0, a1);  DOT(6, a0, a1);  DOT(7, a0, a1);         \
        DOT(8, a0, a1);  DOT(9, a0, a1);  DOT(10, a0, a1); DOT(11, a0, a1);        \
        DOT(12, a0, a1); DOT(13, a0, a1); DOT(14, a0, a1); DOT(15, a0, a1);        \
        float hg = (a0.x + a0.y) + (a1.x + a1.y);                                  \
        if (wid != 2) {                                                            \
            /* retire oldest ring load; consumers tied to the waited reg */        \
            asm volatile("s_waitcnt vmcnt(3)" : "+v"(x##SL));                      \
            float g_ = fsigmoid(x##SL + hg + bias);                                \
            (wid == 0 ? r_lds : z_lds)[lane] = g_;                                 \
            asm volatile("global_load_dword %0, %1, off"                           \
                         : "=v"(x##SL) : "v"(Pd + (size_t)tN_ * 192));             \
        }                                                                          \
        asm volatile("s_waitcnt lgkmcnt(0)" ::: "memory");  /* r,z + all h-reads retired */ \
        __builtin_amdgcn_s_barrier();                        /* B: r,z visible to wave2 */  \
        __builtin_amdgcn_sched_barrier(0);                                         \
        if (wid == 2) {                                                            \
            asm volatile("s_waitcnt vmcnt(3)" : "+v"(x##SL));                      \
            float r_ = r_lds[lane];                                                \
            float z_ = z_lds[lane];                                                \
            float n_ = ftanh(x##SL + r_ * (hg + bias));                            \
            h = fmaf(z_, h - n_, n_);          /* (1-z)*n + z*h */                 \
            sum += h;                                                              \
            mx = fmaxf(mx, h);                                                     \
            h_lds[lane] = h;                                                       \
            asm volatile("global_load_dword %0, %1, off"                           \
                         : "=v"(x##SL) : "v"(Pd + (size_t)tN_ * 192));             \
        }                                                                          \
        asm volatile("s_waitcnt lgkmcnt(0)" ::: "memory");  /* h write retired */  \
        __builtin_amdgcn_s_barrier();                        /* C: h visible to all */      \
        __builtin_amdgcn_sched_barrier(0);                                         \
    } while (0)

    for (int s = 0; s < TLEN; s += 4) {
        GRU_STEP(0, s + 0);
        GRU_STEP(1, s + 1);
        GRU_STEP(2, s + 2);
        GRU_STEP(3, s + 3);
    }
    // drain the 4 tail prefetches per wave (clamped addresses, values dead)
    asm volatile("s_waitcnt vmcnt(0)" ::: "memory");

    // feats layout [b][256]: [mean_f | mean_b | max_f | max_b]
    if (wid == 2) {
        g_feats[b * 256 + dir * 64 + lane] = sum * (1.f / TLEN);
        g_feats[b * 256 + 128 + dir * 64 + lane] = mx;
    }
#undef GRU_PRE
#undef GRU_STEP
#undef DOT
}

// ---------------- Kernel C: classifier  out = W2 @ gelu(W1 @ feats + b1) + b2 ----------------
__global__ __launch_bounds__(64) void classifier(
    const float* __restrict__ w1, const float* __restrict__ b1,
    const float* __restrict__ w2, const float* __restrict__ b2,
    float* __restrict__ out)
{
    const int b = blockIdx.x;
    const int i = threadIdx.x;
    __shared__ float f[256];
    __shared__ float hid[64];
    for (int c = i; c < 256; c += 64) f[c] = g_feats[b * 256 + c];
    __syncthreads();

    float acc = b1[i];
    const float* wrow = w1 + (size_t)i * 256;
#pragma unroll 16
    for (int c = 0; c < 256; c++) acc = fmaf(f[c], wrow[c], acc);
    // exact GELU: x * 0.5 * (1 + erf(x/sqrt(2)))
    hid[i] = acc * 0.5f * (1.f + erff(acc * 0.70710678118654752f));
    __syncthreads();

    if (i < NCLS) {
        float o = b2[i];
        const float* w2r = w2 + (size_t)i * 64;
#pragma unroll
        for (int j = 0; j < 64; j++) o = fmaf(hid[j], w2r[j], o);
        out[b * NCLS + i] = o;
    }
}

extern "C" void kernel_launch(void* const* d_in, const int* in_sizes, int n_in,
                              void* d_out, int out_size, void* d_ws, size_t ws_size,
                              hipStream_t stream) {
    const int*   tokens = (const int*)  d_in[0];
    const float* emb    = (const float*)d_in[1];
    const float* wih_f  = (const float*)d_in[2];
    const float* whh_f  = (const float*)d_in[3];
    const float* bih_f  = (const float*)d_in[4];
    const float* bhh_f  = (const float*)d_in[5];
    const float* wih_b  = (const float*)d_in[6];
    const float* whh_b  = (const float*)d_in[7];
    const float* bih_b  = (const float*)d_in[8];
    const float* bhh_b  = (const float*)d_in[9];
    const float* w1     = (const float*)d_in[10];
    const float* b1     = (const float*)d_in[11];
    const float* w2     = (const float*)d_in[12];
    const float* b2     = (const float*)d_in[13];
    float* out = (float*)d_out;

    precompute_P<<<4096, 384, 0, stream>>>(emb, wih_f, bih_f, wih_b, bih_b);
    gru_seq<<<2 * BATCH, 192, 0, stream>>>(tokens, whh_f, bhh_f, whh_b, bhh_b);
    classifier<<<BATCH, 64, 0, stream>>>(w1, b1, w2, b2, out);
}

// Round 7
// 972.812 us; speedup vs baseline: 1.0095x; 1.0095x over previous
//
#include <hip/hip_runtime.h>
#include <hip/hip_bf16.h>
#include <math.h>

#define VOCAB 50257
#define NCLS 20
#define EDIM 64
#define HDIM 64
#define BATCH 128
#define TLEN 2048

typedef float v2f __attribute__((ext_vector_type(2)));

// Static device scratch: no dependence on ws_size, graph-capture safe.
__device__ float g_P[(size_t)2 * VOCAB * 192];   // 77.2 MB, input-projected vocab table (bias folded)
__device__ float g_feats[BATCH * 256];           // pooled features

__device__ __forceinline__ float fast_rcp(float x) { return __builtin_amdgcn_rcpf(x); }

__device__ __forceinline__ float fsigmoid(float x) {
    // 1/(1+exp(-x)); saturates correctly at +-inf
    return fast_rcp(1.f + __expf(-x));
}
__device__ __forceinline__ float ftanh(float x) {
    // 1 - 2/(exp(2x)+1); saturates correctly at +-inf
    float e = __expf(2.f * x);
    return 1.f - 2.f * fast_rcp(e + 1.f);
}

// ---------------- Kernel A: P[dir][v][g] = dot(emb[v], wih[dir][g]) + bih[dir][g] ----------------
__global__ __launch_bounds__(384) void precompute_P(
    const float* __restrict__ emb,
    const float* __restrict__ wih_f, const float* __restrict__ bih_f,
    const float* __restrict__ wih_b, const float* __restrict__ bih_b)
{
    const int t = threadIdx.x;          // 0..383 ; waves are uniform in (dir), contiguous in g
    const int dir = t / 192;
    const int g = t % 192;
    const float* wih = dir ? wih_b : wih_f;
    const float* bih = dir ? bih_b : bih_f;

    float4 wq0, wq1, wq2, wq3, wq4, wq5, wq6, wq7;
    float4 wq8, wq9, wq10, wq11, wq12, wq13, wq14, wq15;
#define LDWQ(K) wq##K = *(const float4*)(wih + (size_t)g * 64 + 4 * K)
    LDWQ(0); LDWQ(1); LDWQ(2); LDWQ(3); LDWQ(4); LDWQ(5); LDWQ(6); LDWQ(7);
    LDWQ(8); LDWQ(9); LDWQ(10); LDWQ(11); LDWQ(12); LDWQ(13); LDWQ(14); LDWQ(15);
#undef LDWQ
    const float bias = bih[g];
    float* Pd = g_P + (size_t)dir * VOCAB * 192;

    for (int v = blockIdx.x * 2; v < VOCAB; v += gridDim.x * 2) {
        const int v1ok = (v + 1 < VOCAB);
        const float4* e0 = (const float4*)(emb + (size_t)v * 64);            // wave-uniform -> scalar loads
        const float4* e1 = (const float4*)(emb + (size_t)(v1ok ? v + 1 : v) * 64);
        float a0 = bias, a1 = bias;
#define PFMA(K) do {                                   \
            float4 x = e0[K];                          \
            float4 y = e1[K];                          \
            a0 = fmaf(x.x, wq##K.x, a0);               \
            a1 = fmaf(y.x, wq##K.x, a1);               \
            a0 = fmaf(x.y, wq##K.y, a0);               \
            a1 = fmaf(y.y, wq##K.y, a1);               \
            a0 = fmaf(x.z, wq##K.z, a0);               \
            a1 = fmaf(y.z, wq##K.z, a1);               \
            a0 = fmaf(x.w, wq##K.w, a0);               \
            a1 = fmaf(y.w, wq##K.w, a1);               \
        } while (0)
        PFMA(0); PFMA(1); PFMA(2); PFMA(3); PFMA(4); PFMA(5); PFMA(6); PFMA(7);
        PFMA(8); PFMA(9); PFMA(10); PFMA(11); PFMA(12); PFMA(13); PFMA(14); PFMA(15);
#undef PFMA
        Pd[(size_t)v * 192 + g] = a0;
        if (v1ok) Pd[(size_t)(v + 1) * 192 + g] = a1;
    }
}

// ---------------- Kernel B: 12 waves per (dir,batch) — 4 waves per gate, 4 lanes per unit ----------------
// DIAGNOSIS CHAIN (rounds 0-6): the register allocator caps this kernel family at ~52-132
// VGPRs no matter what launch_bounds/waves_per_eu say, so any per-lane weight set of 64+
// floats is scratch-backed and reloaded through tracked vmem EVERY step; the compiler's own
// waits for those reloads serialize each step (~1000 cyc invariant). Fix: make the demand
// fit under the cap BY CONSTRUCTION. Each output unit u of gate g is computed by a 4-lane
// group: lane holds 16 weight floats (8 v2f) and a 16-element partial dot; 2x __shfl_xor
// (DPP quad-perm, register-only) reduces the quad. Demand ~44 VGPR < 52 => spill-free.
//
// Carried over unchanged from the verified structure: depth-4 inline-asm ring with
// s_waitcnt vmcnt(3) tied to the consumed register; raw s_barrier + asm lgkmcnt(0) only
// (never __syncthreads in-loop: its vmcnt(0) drain kills the ring); 2 barriers per step.
// NOTE: the 4-way dot split changes f32 summation order vs rounds 0-6 (absmax becomes
// small-nonzero instead of 0.0).
__global__ __launch_bounds__(768, 1) void gru_seq(
    const int* __restrict__ tokens,
    const float* __restrict__ whh_f, const float* __restrict__ bhh_f,
    const float* __restrict__ whh_b, const float* __restrict__ bhh_b)
{
    const int tid = threadIdx.x;
    const int gate = tid >> 8;           // 0=r, 1=z, 2=n  (4 whole waves per gate -> wave-uniform)
    const int j = tid & 255;
    const int u = j >> 2;                // output unit 0..63
    const int c = j & 3;                 // K-chunk 0..3 (16 h elements each)
    const int blk = blockIdx.x;          // 0..255
    const int b = blk >> 1;
    const int dir = blk & 1;
    const float* whh = dir ? whh_b : whh_f;
    const float* bhh = dir ? bhh_b : bhh_f;
    // gather address for this gate's element of unit u (4 lanes share it; coalesces fine)
    const float* Pd = g_P + (size_t)dir * VOCAB * 192 + gate * 64 + u;

    __shared__ __align__(16) float h_lds[64];
    __shared__ float r_lds[64];
    __shared__ float z_lds[64];
    __shared__ __align__(16) int tok_lds[TLEN];

    // stage token row (8 KB) once
    {
        const int4* src = (const int4*)(tokens + (size_t)b * TLEN);
        int4* dst = (int4*)tok_lds;
        for (int t = tid; t < TLEN / 4; t += 768) dst[t] = src[t];
    }

    // this lane's 16 weight floats -> 8 named v2f regs (register-resident: total demand ~44)
    v2f w0, w1, w2, w3, w4, w5, w6, w7;
    {
        const float4* p = (const float4*)(whh + (size_t)(gate * 64 + u) * 64 + c * 16);
        float4 q0 = p[0]; w0 = (v2f){q0.x, q0.y}; w1 = (v2f){q0.z, q0.w};
        float4 q1 = p[1]; w2 = (v2f){q1.x, q1.y}; w3 = (v2f){q1.z, q1.w};
        float4 q2 = p[2]; w4 = (v2f){q2.x, q2.y}; w5 = (v2f){q2.z, q2.w};
        float4 q3 = p[3]; w6 = (v2f){q3.x, q3.y}; w7 = (v2f){q3.z, q3.w};
    }
    const float bias = bhh[gate * 64 + u];

    if (tid < 64) h_lds[tid] = 0.f;
    float h = 0.f, sum = 0.f, mx = -INFINITY;   // live in gate-2 lanes only
    __syncthreads();    // prologue-only: tok_lds + h_lds visible (ring not yet started)

    // time mapping: step s -> tt = dir ? T-1-s : s
    auto tok_at = [&](int s) -> int {
        int ss = s < TLEN ? s : TLEN - 1;        // clamp for tail prefetches (values unused)
        return tok_lds[dir ? (TLEN - 1 - ss) : ss];
    };

    // depth-4 ring: 4 named regs, defined ONLY by asm loads (1 dword/lane/step)
    float x0, x1, x2, x3;
#define GRU_PRE(SL, D) \
    asm volatile("global_load_dword %0, %1, off" : "=v"(x##SL) : "v"(Pd + (size_t)tok_at(D) * 192))
    GRU_PRE(0, 0); GRU_PRE(1, 1); GRU_PRE(2, 2); GRU_PRE(3, 3);

#define GRU_STEP(SL, SB) do {                                                      \
        const int tN_ = tok_at((SB) + 4);   /* broadcast LDS read, off critical path */ \
        const float4* hb_ = (const float4*)(h_lds + c * 16);                       \
        v2f a0 = {0.f, 0.f}, a1 = {0.f, 0.f};                                      \
        { float4 h4_ = hb_[0];                                                     \
          a0 = __builtin_elementwise_fma((v2f){h4_.x, h4_.y}, w0, a0);             \
          a1 = __builtin_elementwise_fma((v2f){h4_.z, h4_.w}, w1, a1); }           \
        { float4 h4_ = hb_[1];                                                     \
          a0 = __builtin_elementwise_fma((v2f){h4_.x, h4_.y}, w2, a0);             \
          a1 = __builtin_elementwise_fma((v2f){h4_.z, h4_.w}, w3, a1); }           \
        { float4 h4_ = hb_[2];                                                     \
          a0 = __builtin_elementwise_fma((v2f){h4_.x, h4_.y}, w4, a0);             \
          a1 = __builtin_elementwise_fma((v2f){h4_.z, h4_.w}, w5, a1); }           \
        { float4 h4_ = hb_[3];                                                     \
          a0 = __builtin_elementwise_fma((v2f){h4_.x, h4_.y}, w6, a0);             \
          a1 = __builtin_elementwise_fma((v2f){h4_.z, h4_.w}, w7, a1); }           \
        float p_ = (a0.x + a0.y) + (a1.x + a1.y);                                  \
        float t_ = p_ + __shfl_xor(p_, 1);          /* quad butterfly (DPP) */     \
        float hg = t_ + __shfl_xor(t_, 2);                                         \
        if (gate != 2) {                                                           \
            /* retire oldest ring load; consumers tied to the waited reg */        \
            asm volatile("s_waitcnt vmcnt(3)" : "+v"(x##SL));                      \
            float g_ = fsigmoid(x##SL + hg + bias);                                \
            if (c == 0) (gate == 0 ? r_lds : z_lds)[u] = g_;                       \
            asm volatile("global_load_dword %0, %1, off"                           \
                         : "=v"(x##SL) : "v"(Pd + (size_t)tN_ * 192));             \
        }                                                                          \
        asm volatile("s_waitcnt lgkmcnt(0)" ::: "memory");  /* r,z + h-reads retired */ \
        __builtin_amdgcn_s_barrier();                        /* B: r,z visible */  \
        __builtin_amdgcn_sched_barrier(0);                                         \
        if (gate == 2) {                                                           \
            asm volatile("s_waitcnt vmcnt(3)" : "+v"(x##SL));                      \
            float r_ = r_lds[u];                                                   \
            float z_ = z_lds[u];                                                   \
            float n_ = ftanh(x##SL + r_ * (hg + bias));                            \
            h = fmaf(z_, h - n_, n_);          /* (1-z)*n + z*h */                 \
            sum += h;                                                              \
            mx = fmaxf(mx, h);                                                     \
            if (c == 0) h_lds[u] = h;                                              \
            asm volatile("global_load_dword %0, %1, off"                           \
                         : "=v"(x##SL) : "v"(Pd + (size_t)tN_ * 192));             \
        }                                                                          \
        asm volatile("s_waitcnt lgkmcnt(0)" ::: "memory");  /* h write retired */  \
        __builtin_amdgcn_s_barrier();                        /* C: h visible */    \
        __builtin_amdgcn_sched_barrier(0);                                         \
    } while (0)

    for (int s = 0; s < TLEN; s += 4) {
        GRU_STEP(0, s + 0);
        GRU_STEP(1, s + 1);
        GRU_STEP(2, s + 2);
        GRU_STEP(3, s + 3);
    }
    // drain the 4 tail prefetches (clamped addresses, values dead)
    asm volatile("s_waitcnt vmcnt(0)" ::: "memory");

    // feats layout [b][256]: [mean_f | mean_b | max_f | max_b]
    if (gate == 2 && c == 0) {
        g_feats[b * 256 + dir * 64 + u] = sum * (1.f / TLEN);
        g_feats[b * 256 + 128 + dir * 64 + u] = mx;
    }
#undef GRU_PRE
#undef GRU_STEP
}

// ---------------- Kernel C: classifier  out = W2 @ gelu(W1 @ feats + b1) + b2 ----------------
__global__ __launch_bounds__(64) void classifier(
    const float* __restrict__ w1, const float* __restrict__ b1,
    const float* __restrict__ w2, const float* __restrict__ b2,
    float* __restrict__ out)
{
    const int b = blockIdx.x;
    const int i = threadIdx.x;
    __shared__ float f[256];
    __shared__ float hid[64];
    for (int c = i; c < 256; c += 64) f[c] = g_feats[b * 256 + c];
    __syncthreads();

    float acc = b1[i];
    const float* wrow = w1 + (size_t)i * 256;
#pragma unroll 16
    for (int c = 0; c < 256; c++) acc = fmaf(f[c], wrow[c], acc);
    // exact GELU: x * 0.5 * (1 + erf(x/sqrt(2)))
    hid[i] = acc * 0.5f * (1.f + erff(acc * 0.70710678118654752f));
    __syncthreads();

    if (i < NCLS) {
        float o = b2[i];
        const float* w2r = w2 + (size_t)i * 64;
#pragma unroll
        for (int j = 0; j < 64; j++) o = fmaf(hid[j], w2r[j], o);
        out[b * NCLS + i] = o;
    }
}

extern "C" void kernel_launch(void* const* d_in, const int* in_sizes, int n_in,
                              void* d_out, int out_size, void* d_ws, size_t ws_size,
                              hipStream_t stream) {
    const int*   tokens = (const int*)  d_in[0];
    const float* emb    = (const float*)d_in[1];
    const float* wih_f  = (const float*)d_in[2];
    const float* whh_f  = (const float*)d_in[3];
    const float* bih_f  = (const float*)d_in[4];
    const float* bhh_f  = (const float*)d_in[5];
    const float* wih_b  = (const float*)d_in[6];
    const float* whh_b  = (const float*)d_in[7];
    const float* bih_b  = (const float*)d_in[8];
    const float* bhh_b  = (const float*)d_in[9];
    const float* w1     = (const float*)d_in[10];
    const float* b1     = (const float*)d_in[11];
    const float* w2     = (const float*)d_in[12];
    const float* b2     = (const float*)d_in[13];
    float* out = (float*)d_out;

    precompute_P<<<4096, 384, 0, stream>>>(emb, wih_f, bih_f, wih_b, bih_b);
    gru_seq<<<2 * BATCH, 768, 0, stream>>>(tokens, whh_f, bhh_f, whh_b, bhh_b);
    classifier<<<BATCH, 64, 0, stream>>>(w1, b1, w2, b2, out);
}